// Round 7
// baseline (143.180 us; speedup 1.0000x reference)
//
#include <hip/hip_runtime.h>
#include <hip/hip_bf16.h>
#include <math.h>

#define D 384
#define EPS 1e-8f

#define RPB 256            // rows per block (4 waves x 64)
#define CPS 512            // cols per split
#define POS_W 128          // cols per position (fold granularity)
#define NPOS 4             // 512/128
#define NKB 6              // 384/64 k-steps (i8: K=64 per MFMA)
#define STG 24576          // stage bytes: 8 KB B (128 cols x 64 B) + 16 KB A (256 rows x 64 B)

typedef int    intx4   __attribute__((ext_vector_type(4)));

// ---------------- kernel 1: rnorm + normalized i8 quant + ws init ----------------
// Vectorized: float4+float2 loads (24 B/lane), int+short stores (6 B/lane) --
// replaces 6 scalar byte-stores per lane. Rows are unit-norm -> uniform scale
// 127 preserves dot RANKING (argmax only; distances recomputed in fp32).
__global__ __launch_bounds__(256) void prep_kernel(const float* __restrict__ in,
                                                   float* __restrict__ rnorm,
                                                   char* __restrict__ xq,
                                                   unsigned long long* __restrict__ best,
                                                   float* __restrict__ out, int N) {
    if (blockIdx.x == 0 && threadIdx.x == 0) *out = 0.f;   // replaces memset node
    int row = blockIdx.x * 4 + (threadIdx.x >> 6);   // one wave per row
    if (row >= N) return;
    int lane = threadIdx.x & 63;
    const float* p = in + (size_t)row * D;
    float4 a = *(const float4*)(p + lane * 4);           // elems 0..255
    float2 b = *(const float2*)(p + 256 + lane * 2);     // elems 256..383
    float s = a.x * a.x + a.y * a.y + a.z * a.z + a.w * a.w + b.x * b.x + b.y * b.y;
#pragma unroll
    for (int off = 32; off >= 1; off >>= 1) s += __shfl_xor(s, off, 64);
    float rn = 1.0f / fmaxf(sqrtf(s), EPS);
    if (lane == 0) { rnorm[row] = rn; best[row] = 0ull; }  // replaces memset node
    const float sc = rn * 127.f;
    int b0 = __float2int_rn(a.x * sc), b1 = __float2int_rn(a.y * sc);
    int b2 = __float2int_rn(a.z * sc), b3 = __float2int_rn(a.w * sc);
    int b4 = __float2int_rn(b.x * sc), b5 = __float2int_rn(b.y * sc);
    char* q = xq + (size_t)row * D;
    *(int*)(q + lane * 4) = (b0 & 0xff) | ((b1 & 0xff) << 8) | ((b2 & 0xff) << 16) | (b3 << 24);
    *(short*)(q + 256 + lane * 2) = (short)((b4 & 0xff) | (b5 << 8));
}

// ---------------- kernel 2: row-ownership i8-MFMA scan (R6 schedule, VALU diet) ----------------
// R6 counters: latency-bound at 2 waves/SIMD; VALU ~25% busy with ~1000 cyc/step
// of addressing (div/mod by 6, full 64-bit glds address rebuilds, runtime
// buffer rotation). Unrolling kb makes (kb+2)%3 / kb%3 COMPILE-TIME (6 = 0 mod 3),
// kills div/mod, and reduces glds addressing to hoisted bases + constants
// (A bases don't depend on pos at all). Schedule itself is byte-identical to
// R6 (stage 2 ahead, vmcnt(6) counted wait, one barrier/step). T5 setprio
// around the MFMA cluster (2 independent blocks/CU = role diversity).
__global__ __launch_bounds__(256, 2) void maxdot_rows(const char* __restrict__ xq,
                                                      unsigned long long* __restrict__ best) {
    __shared__ char Bs[3][STG];

    const int t    = threadIdx.x;
    const int lane = t & 63;
    const int wv   = t >> 6;
    const int quad = lane >> 4, l16 = lane & 15;
    const int rb   = blockIdx.x >> 4;                // 32 row-blocks
    const int cs   = blockIdx.x & 15;                // 16 col-splits
    const int row0b = rb * RPB;
    const int col0s = cs * CPS;
    const int wrow0 = row0b + wv * 64;

    intx4 acc[4][8];
#pragma unroll
    for (int mi = 0; mi < 4; ++mi)
#pragma unroll
        for (int ni = 0; ni < 8; ++ni) acc[mi][ni] = (intx4){0, 0, 0, 0};

    int rv[16];
    int ri[16];
#pragma unroll
    for (int i = 0; i < 16; ++i) { rv[i] = -0x7fffffff; ri[i] = 0; }

    // staging: thread t owns granule sg = t&3 of B-cols {sc, sc+64} and
    // A-rows {sc, sc+64, sc+128, sc+192}, sc = t>>2. 6 x 16 B = 96 B/thread.
    const int sc = t >> 2;
    const int sg = t & 3;

    // hoisted global base pointers (A bases are pos-invariant)
    const char* colB0 = xq + (size_t)(col0s + sc)         * 384 + sg * 16;
    const char* colB1 = xq + (size_t)(col0s + 64 + sc)    * 384 + sg * 16;
    const char* rowA0 = xq + (size_t)(row0b + sc)         * 384 + sg * 16;
    const char* rowA1 = xq + (size_t)(row0b + 64 + sc)    * 384 + sg * 16;
    const char* rowA2 = xq + (size_t)(row0b + 128 + sc)   * 384 + sg * 16;
    const char* rowA3 = xq + (size_t)(row0b + 192 + sc)   * 384 + sg * 16;

#define GLDS(SRC, DST) __builtin_amdgcn_global_load_lds(                               \
        (const __attribute__((address_space(1))) void*)(SRC),                          \
        (__attribute__((address_space(3))) void*)(DST), 16, 0, 0)

#define STAGE(CO, KB, BUF) do {                                                        \
        GLDS(colB0 + (CO) + (KB) * 64, (BUF) +         t * 16);                        \
        GLDS(colB1 + (CO) + (KB) * 64, (BUF) +  4096 + t * 16);                        \
        GLDS(rowA0 +        (KB) * 64, (BUF) +  8192 + t * 16);                        \
        GLDS(rowA1 +        (KB) * 64, (BUF) + 12288 + t * 16);                        \
        GLDS(rowA2 +        (KB) * 64, (BUF) + 16384 + t * 16);                        \
        GLDS(rowA3 +        (KB) * 64, (BUF) + 20480 + t * 16);                        \
    } while (0)

    // prologue: 2 stages (12 glds) in flight
    STAGE(0, 0, Bs[0]);
    STAGE(0, 1, Bs[1]);

    const int lofs = l16 * 64 + quad * 16;           // reader byte within a 64-B k-chunk

    for (int pos = 0; pos < NPOS; ++pos) {
        const int colbase = col0s + pos * POS_W;
#pragma unroll
        for (int kb = 0; kb < NKB; ++kb) {
            // stage(tt) complete; stage(tt+1) (6 glds) stays in flight across barrier
            if (kb == NKB - 1 && pos == NPOS - 1)
                asm volatile("s_waitcnt vmcnt(0)" ::: "memory");
            else
                asm volatile("s_waitcnt vmcnt(6)" ::: "memory");
            __builtin_amdgcn_s_barrier();
            __builtin_amdgcn_sched_barrier(0);

            // stage tile tt+2 into the buffer all waves finished reading at tt-1
            // (buffer index (kb+2)%3 is compile-time after unroll)
            if (kb < NKB - 2) {
                STAGE((size_t)pos * (POS_W * 384), kb + 2, Bs[(kb + 2) % 3]);
            } else if (pos < NPOS - 1) {
                STAGE((size_t)(pos + 1) * (POS_W * 384), kb + 2 - NKB, Bs[(kb + 2) % 3]);
            }

            // A and B fragments from LDS (staged ~2 k-steps ago); all 12
            // ds_reads issued together -> single latency exposure
            const char* bb = Bs[kb % 3];
            const char* Ab = bb + 8192 + wv * 4096;  // this wave's 64 rows
            intx4 af[4];
#pragma unroll
            for (int mi = 0; mi < 4; ++mi)
                af[mi] = *(const intx4*)(Ab + mi * 1024 + lofs);
            intx4 bfr[8];
#pragma unroll
            for (int ni = 0; ni < 8; ++ni)
                bfr[ni] = *(const intx4*)(bb + ni * 1024 + lofs);
            __builtin_amdgcn_s_setprio(1);
#pragma unroll
            for (int mi = 0; mi < 4; ++mi)
#pragma unroll
                for (int ni = 0; ni < 8; ++ni)
                    acc[mi][ni] = __builtin_amdgcn_mfma_i32_16x16x64_i8(af[mi], bfr[ni], acc[mi][ni], 0, 0, 0);
            __builtin_amdgcn_s_setprio(0);

            // ---- end of a position: fold into running (val, col); zero acc ----
            if (kb == NKB - 1) {
                const bool dg = (colbase < row0b + RPB) && (row0b < colbase + POS_W);
#pragma unroll
                for (int mi = 0; mi < 4; ++mi)
#pragma unroll
                    for (int reg = 0; reg < 4; ++reg) {
                        const int r = wrow0 + mi * 16 + quad * 4 + reg;
                        int d[8];
#pragma unroll
                        for (int ni = 0; ni < 8; ++ni) d[ni] = acc[mi][ni][reg];
                        if (dg) {
#pragma unroll
                            for (int ni = 0; ni < 8; ++ni)
                                if (colbase + ni * 16 + l16 == r) d[ni] = -0x40000000;
                        }
                        int m = d[0]; int ci = 0;
#pragma unroll
                        for (int ni = 1; ni < 8; ++ni) {     // ties -> lower ni (lower col)
                            bool gt = d[ni] > m;
                            m  = gt ? d[ni] : m;
                            ci = gt ? ni : ci;
                        }
                        const int slot = mi * 4 + reg;
                        bool upd = m > rv[slot];             // ties -> earlier position (lower col)
                        rv[slot] = upd ? m : rv[slot];
                        ri[slot] = upd ? (colbase + ci * 16 + l16) : ri[slot];
#pragma unroll
                        for (int ni = 0; ni < 8; ++ni) acc[mi][ni][reg] = 0;
                    }
            }
        }
    }
#undef STAGE
#undef GLDS

    // ---- final cross-lane reduce over the 16 col-lanes, one atomic per row ----
#pragma unroll
    for (int slot = 0; slot < 16; ++slot) {
        int v = rv[slot]; int ci = ri[slot];
#pragma unroll
        for (int m = 1; m < 16; m <<= 1) {
            int ov = __shfl_xor(v, m, 64);
            int oi = __shfl_xor(ci, m, 64);
            bool take = (ov > v) || (ov == v && oi < ci);
            v  = take ? ov : v;
            ci = take ? oi : ci;
        }
        if (l16 == 0) {
            const int r = wrow0 + (slot >> 2) * 16 + quad * 4 + (slot & 3);
            unsigned u = ((unsigned)v) ^ 0x80000000u;    // monotone int -> unsigned
            unsigned long long key = ((unsigned long long)u << 32) | (unsigned)(~ci);
            atomicMax(best + r, key);
        }
    }
}

// ---------------- kernel 3: exact fp32 distance + loss ----------------
__global__ __launch_bounds__(256) void loss_kernel(const float* __restrict__ in,
                                                   const float* __restrict__ rnorm,
                                                   const unsigned long long* __restrict__ best,
                                                   float* __restrict__ out, int N) {
    __shared__ float part[4];
    const int wave = threadIdx.x >> 6, lane = threadIdx.x & 63;
    const int gw = blockIdx.x * 4 + wave;            // 1024 waves total
    float local = 0.f;
    for (int row = gw; row < N; row += 1024) {
        unsigned long long key = best[row];
        int j = (int)(~(unsigned)(key & 0xffffffffull));
        float rni = rnorm[row], rnj = rnorm[j];
        const float* pi = in + (size_t)row * D;
        const float* pj = in + (size_t)j * D;
        float s = 0.f;
#pragma unroll
        for (int c = 0; c < 6; ++c) {
            float xi = pi[lane + 64 * c] * rni;
            float xj = pj[lane + 64 * c] * rnj;
            float dvv = xi - xj + EPS;               // ||x - nn_x + eps||
            s += dvv * dvv;
        }
#pragma unroll
        for (int off = 32; off > 0; off >>= 1) s += __shfl_down(s, off, 64);
        if (lane == 0) local += -logf(sqrtf(s) + EPS);
    }
    if (lane == 0) part[wave] = local;
    __syncthreads();
    if (threadIdx.x == 0)
        atomicAdd(out, (part[0] + part[1] + part[2] + part[3]) / (float)N);
}

extern "C" void kernel_launch(void* const* d_in, const int* in_sizes, int n_in,
                              void* d_out, int out_size, void* d_ws, size_t ws_size,
                              hipStream_t stream) {
    const float* in = (const float*)d_in[0];
    float* out = (float*)d_out;
    const int N = in_sizes[0] / D;                   // 8192

    // workspace layout: rnorm (N f32) | best (N u64) | xq (N*D i8)
    char* ws = (char*)d_ws;
    float* rnorm = (float*)ws;
    unsigned long long* best = (unsigned long long*)(ws + 64 * 1024);
    char* xq = ws + 192 * 1024;

    // best/out zeroing folded into prep_kernel
    prep_kernel<<<N / 4, 256, 0, stream>>>(in, rnorm, xq, best, out, N);
    maxdot_rows<<<512, 256, 0, stream>>>(xq, best);        // 32 row-blocks x 16 col-splits
    loss_kernel<<<256, 256, 0, stream>>>(in, rnorm, best, out, N);
}

// Round 8
// 105.789 us; speedup vs baseline: 1.3535x; 1.3535x over previous
//
#include <hip/hip_runtime.h>
#include <hip/hip_bf16.h>
#include <math.h>

#define D 384
#define EPS 1e-8f

#define RPB 256            // rows per block (4 waves x 64)
#define CPS 512            // cols per split
#define POS_W 128          // cols per position (fold granularity)
#define NPOS 4             // 512/128
#define NKB 6              // 384/64 k-steps (i8: K=64 per MFMA)
#define NT  24             // NPOS * NKB tiles per block
#define STG 24576          // stage bytes: 8 KB B (128 cols x 64 B) + 16 KB A (256 rows x 64 B)

typedef int    intx4   __attribute__((ext_vector_type(4)));

// ---------------- kernel 1: rnorm + normalized i8 quant + ws init ----------------
// Vectorized: float4+float2 loads (24 B/lane), int+short stores (6 B/lane).
// Rows are unit-norm -> uniform scale 127 preserves dot RANKING (argmax only;
// distances recomputed in exact fp32 from the index).
__global__ __launch_bounds__(256) void prep_kernel(const float* __restrict__ in,
                                                   float* __restrict__ rnorm,
                                                   char* __restrict__ xq,
                                                   unsigned long long* __restrict__ best,
                                                   float* __restrict__ out, int N) {
    if (blockIdx.x == 0 && threadIdx.x == 0) *out = 0.f;   // replaces memset node
    int row = blockIdx.x * 4 + (threadIdx.x >> 6);   // one wave per row
    if (row >= N) return;
    int lane = threadIdx.x & 63;
    const float* p = in + (size_t)row * D;
    float4 a = *(const float4*)(p + lane * 4);           // elems 0..255
    float2 b = *(const float2*)(p + 256 + lane * 2);     // elems 256..383
    float s = a.x * a.x + a.y * a.y + a.z * a.z + a.w * a.w + b.x * b.x + b.y * b.y;
#pragma unroll
    for (int off = 32; off >= 1; off >>= 1) s += __shfl_xor(s, off, 64);
    float rn = 1.0f / fmaxf(sqrtf(s), EPS);
    if (lane == 0) { rnorm[row] = rn; best[row] = 0ull; }  // replaces memset node
    const float sc = rn * 127.f;
    int b0 = __float2int_rn(a.x * sc), b1 = __float2int_rn(a.y * sc);
    int b2 = __float2int_rn(a.z * sc), b3 = __float2int_rn(a.w * sc);
    int b4 = __float2int_rn(b.x * sc), b5 = __float2int_rn(b.y * sc);
    char* q = xq + (size_t)row * D;
    *(int*)(q + lane * 4) = (b0 & 0xff) | ((b1 & 0xff) << 8) | ((b2 & 0xff) << 16) | (b3 << 24);
    *(short*)(q + 256 + lane * 2) = (short)((b4 & 0xff) | (b5 << 8));
}

// ---------------- kernel 2: row-ownership i8-MFMA scan (R6 schedule, REVERTED) ----------------
// R7 lesson: fully unrolling kb inflated the scheduler's live-range window ->
// compiler spilled the 512-B/thread acc array to scratch (WRITE_SIZE 4->72 MB,
// MfmaUtil 26->13%). The runtime-tt loop with pointer rotation (this version,
// measured ~41 us / VGPR 108 / no spills) is the best-known schedule: stage
// 2 ahead, vmcnt(6) counted wait, one barrier/step, ALL 12 frag ds_reads
// issued together, mi-outer MFMA. Do not unroll; do not add setprio here.
__global__ __launch_bounds__(256, 2) void maxdot_rows(const char* __restrict__ xq,
                                                      unsigned long long* __restrict__ best) {
    __shared__ char Bs[3][STG];

    const int t    = threadIdx.x;
    const int lane = t & 63;
    const int wv   = t >> 6;
    const int quad = lane >> 4, l16 = lane & 15;
    const int rb   = blockIdx.x >> 4;                // 32 row-blocks
    const int cs   = blockIdx.x & 15;                // 16 col-splits
    const int row0b = rb * RPB;
    const int col0s = cs * CPS;
    const int wrow0 = row0b + wv * 64;

    intx4 acc[4][8];
#pragma unroll
    for (int mi = 0; mi < 4; ++mi)
#pragma unroll
        for (int ni = 0; ni < 8; ++ni) acc[mi][ni] = (intx4){0, 0, 0, 0};

    int rv[16];
    int ri[16];
#pragma unroll
    for (int i = 0; i < 16; ++i) { rv[i] = -0x7fffffff; ri[i] = 0; }

    // staging: thread t owns granule sg = t&3 of B-cols {sc, sc+64} and
    // A-rows {sc, sc+64, sc+128, sc+192}, sc = t>>2. 6 x 16 B = 96 B/thread.
    const int sc = t >> 2;
    const int sg = t & 3;

#define GLDS(SRC, DST) __builtin_amdgcn_global_load_lds(                               \
        (const __attribute__((address_space(1))) void*)(SRC),                          \
        (__attribute__((address_space(3))) void*)(DST), 16, 0, 0)

#define STAGE(TT, BUF) do {                                                            \
        const int p_  = (TT) / NKB, kb_ = (TT) - p_ * NKB;                             \
        const int cb_ = col0s + p_ * POS_W;                                            \
        const size_t ko_ = (size_t)kb_ * 64 + sg * 16;                                 \
        GLDS(xq + (size_t)(cb_ + sc)        * 384 + ko_, (BUF) +         t * 16);      \
        GLDS(xq + (size_t)(cb_ + 64 + sc)   * 384 + ko_, (BUF) +  4096 + t * 16);      \
        GLDS(xq + (size_t)(row0b + sc)      * 384 + ko_, (BUF) +  8192 + t * 16);      \
        GLDS(xq + (size_t)(row0b + 64 + sc) * 384 + ko_, (BUF) + 12288 + t * 16);      \
        GLDS(xq + (size_t)(row0b + 128 + sc)* 384 + ko_, (BUF) + 16384 + t * 16);      \
        GLDS(xq + (size_t)(row0b + 192 + sc)* 384 + ko_, (BUF) + 20480 + t * 16);      \
    } while (0)

    // prologue: 2 stages (12 glds) in flight
    STAGE(0, Bs[0]);
    STAGE(1, Bs[1]);

    char* b0 = Bs[0];                                // read this iter
    char* b1 = Bs[1];                                // read next iter
    char* b2 = Bs[2];                                // stage target this iter

    const int lofs = l16 * 64 + quad * 16;           // reader byte within a 64-B k-chunk

    for (int tt = 0; tt < NT; ++tt) {
        const int pos = tt / NKB, kb = tt - pos * NKB;
        const int colbase = col0s + pos * POS_W;

        // stage(tt) complete; stage(tt+1) (6 glds) stays in flight across barrier
        if (tt < NT - 1) asm volatile("s_waitcnt vmcnt(6)" ::: "memory");
        else             asm volatile("s_waitcnt vmcnt(0)" ::: "memory");
        __builtin_amdgcn_s_barrier();
        __builtin_amdgcn_sched_barrier(0);

        // stage tile tt+2 into the buffer all waves finished reading at tt-1
        if (tt + 2 < NT) STAGE(tt + 2, b2);

        // A and B fragments from LDS (prefetched ~2 k-steps ago); all 12
        // ds_reads issued together -> single latency exposure
        const char* Ab = b0 + 8192 + wv * 4096;      // this wave's 64 rows
        intx4 af[4];
#pragma unroll
        for (int mi = 0; mi < 4; ++mi)
            af[mi] = *(const intx4*)(Ab + mi * 1024 + lofs);
        intx4 bfr[8];
#pragma unroll
        for (int ni = 0; ni < 8; ++ni)
            bfr[ni] = *(const intx4*)(b0 + ni * 1024 + lofs);
#pragma unroll
        for (int mi = 0; mi < 4; ++mi)
#pragma unroll
            for (int ni = 0; ni < 8; ++ni)
                acc[mi][ni] = __builtin_amdgcn_mfma_i32_16x16x64_i8(af[mi], bfr[ni], acc[mi][ni], 0, 0, 0);

        // ---- end of a position: fold into running (val, col); zero acc ----
        if (kb == NKB - 1) {
            const bool dg = (colbase < row0b + RPB) && (row0b < colbase + POS_W);
#pragma unroll
            for (int mi = 0; mi < 4; ++mi)
#pragma unroll
                for (int reg = 0; reg < 4; ++reg) {
                    const int r = wrow0 + mi * 16 + quad * 4 + reg;
                    int d[8];
#pragma unroll
                    for (int ni = 0; ni < 8; ++ni) d[ni] = acc[mi][ni][reg];
                    if (dg) {
#pragma unroll
                        for (int ni = 0; ni < 8; ++ni)
                            if (colbase + ni * 16 + l16 == r) d[ni] = -0x40000000;
                    }
                    int m = d[0]; int ci = 0;
#pragma unroll
                    for (int ni = 1; ni < 8; ++ni) {     // ties -> lower ni (lower col)
                        bool gt = d[ni] > m;
                        m  = gt ? d[ni] : m;
                        ci = gt ? ni : ci;
                    }
                    const int slot = mi * 4 + reg;
                    bool upd = m > rv[slot];             // ties -> earlier position (lower col)
                    rv[slot] = upd ? m : rv[slot];
                    ri[slot] = upd ? (colbase + ci * 16 + l16) : ri[slot];
#pragma unroll
                    for (int ni = 0; ni < 8; ++ni) acc[mi][ni][reg] = 0;
                }
        }

        // rotate buffers
        char* tmp = b0; b0 = b1; b1 = b2; b2 = tmp;
    }
#undef STAGE
#undef GLDS

    // ---- final cross-lane reduce over the 16 col-lanes, one atomic per row ----
#pragma unroll
    for (int slot = 0; slot < 16; ++slot) {
        int v = rv[slot]; int ci = ri[slot];
#pragma unroll
        for (int m = 1; m < 16; m <<= 1) {
            int ov = __shfl_xor(v, m, 64);
            int oi = __shfl_xor(ci, m, 64);
            bool take = (ov > v) || (ov == v && oi < ci);
            v  = take ? ov : v;
            ci = take ? oi : ci;
        }
        if (l16 == 0) {
            const int r = wrow0 + (slot >> 2) * 16 + quad * 4 + (slot & 3);
            unsigned u = ((unsigned)v) ^ 0x80000000u;    // monotone int -> unsigned
            unsigned long long key = ((unsigned long long)u << 32) | (unsigned)(~ci);
            atomicMax(best + r, key);
        }
    }
}

// ---------------- kernel 3: exact fp32 distance + loss ----------------
__global__ __launch_bounds__(256) void loss_kernel(const float* __restrict__ in,
                                                   const float* __restrict__ rnorm,
                                                   const unsigned long long* __restrict__ best,
                                                   float* __restrict__ out, int N) {
    __shared__ float part[4];
    const int wave = threadIdx.x >> 6, lane = threadIdx.x & 63;
    const int gw = blockIdx.x * 4 + wave;            // 1024 waves total
    float local = 0.f;
    for (int row = gw; row < N; row += 1024) {
        unsigned long long key = best[row];
        int j = (int)(~(unsigned)(key & 0xffffffffull));
        float rni = rnorm[row], rnj = rnorm[j];
        const float* pi = in + (size_t)row * D;
        const float* pj = in + (size_t)j * D;
        float s = 0.f;
#pragma unroll
        for (int c = 0; c < 6; ++c) {
            float xi = pi[lane + 64 * c] * rni;
            float xj = pj[lane + 64 * c] * rnj;
            float dvv = xi - xj + EPS;               // ||x - nn_x + eps||
            s += dvv * dvv;
        }
#pragma unroll
        for (int off = 32; off > 0; off >>= 1) s += __shfl_down(s, off, 64);
        if (lane == 0) local += -logf(sqrtf(s) + EPS);
    }
    if (lane == 0) part[wave] = local;
    __syncthreads();
    if (threadIdx.x == 0)
        atomicAdd(out, (part[0] + part[1] + part[2] + part[3]) / (float)N);
}

extern "C" void kernel_launch(void* const* d_in, const int* in_sizes, int n_in,
                              void* d_out, int out_size, void* d_ws, size_t ws_size,
                              hipStream_t stream) {
    const float* in = (const float*)d_in[0];
    float* out = (float*)d_out;
    const int N = in_sizes[0] / D;                   // 8192

    // workspace layout: rnorm (N f32) | best (N u64) | xq (N*D i8)
    char* ws = (char*)d_ws;
    float* rnorm = (float*)ws;
    unsigned long long* best = (unsigned long long*)(ws + 64 * 1024);
    char* xq = ws + 192 * 1024;

    // best/out zeroing folded into prep_kernel
    prep_kernel<<<N / 4, 256, 0, stream>>>(in, rnorm, xq, best, out, N);
    maxdot_rows<<<512, 256, 0, stream>>>(xq, best);        // 32 row-blocks x 16 col-splits
    loss_kernel<<<256, 256, 0, stream>>>(in, rnorm, best, out, N);
}